// Round 9
// baseline (257.753 us; speedup 1.0000x reference)
//
#include <hip/hip_runtime.h>
#include <stdint.h>

#define NB   8192
#define DIN  512
#define NH1  4096
#define NH2  4096
#define NA   64

typedef int v4i __attribute__((ext_vector_type(4)));

__device__ __forceinline__ v4i mfma_i8(v4i a, v4i b, v4i c) {
    return __builtin_amdgcn_mfma_i32_16x16x64_i8(a, b, c, 0, 0, 0);
}

// ---- async global->LDS, 16B per lane (dest = wave-uniform base + lane*16) ----
__device__ __forceinline__ void gload16(const void* g, const void* l) {
    __builtin_amdgcn_global_load_lds(
        (const __attribute__((address_space(1))) void*)(uintptr_t)g,
        (__attribute__((address_space(3))) void*)(uint32_t)(uintptr_t)l,
        16, 0, 0);
}

// ---------------- merged prep: all converts + sum_wp in ONE launch ----------------
// blocks [0,16384): w2 cvt | [16384,18432): w1 cvt | [18432,19456): x frag
// [19456,19520): wp frag | [19520,19584): sum_wp
__global__ __launch_bounds__(256)
void prep(const float* __restrict__ x,  const float* __restrict__ w1,
          const float* __restrict__ w2, const float* __restrict__ wp,
          signed char* __restrict__ xf, signed char* __restrict__ w1_i8,
          signed char* __restrict__ w2_i8, signed char* __restrict__ wpf,
          int* __restrict__ S)
{
    __shared__ int red[256];
    const int b   = blockIdx.x;
    const int tid = threadIdx.x;

    if (b < 18432) {   // plain i8 converts (float4 -> char4)
        const float* in  = (b < 16384) ? w2 : w1;
        signed char* out = (b < 16384) ? w2_i8 : w1_i8;
        const int i = ((b < 16384) ? b : (b - 16384)) * 256 + tid;
        const float4 v = ((const float4*)in)[i];
        char4 c;
        c.x = (signed char)__float2int_rn(v.x);
        c.y = (signed char)__float2int_rn(v.y);
        c.z = (signed char)__float2int_rn(v.z);
        c.w = (signed char)__float2int_rn(v.w);
        ((char4*)out)[i] = c;
    } else if (b < 19456) {   // x -> fragment layout (K=512, KT=8)
        const int u   = (b - 18432) * 256 + tid;       // 262144 units
        const int g   = u >> 9;
        const int kt  = (u >> 6) & 7;
        const int l   = u & 63;
        const int row = g * 16 + (l & 15);
        const int k0  = kt * 64 + (l >> 4) * 16;
        const float4* src = (const float4*)(x + (size_t)row * DIN + k0);
        signed char v[16];
        #pragma unroll
        for (int q = 0; q < 4; ++q) {
            const float4 f = src[q];
            v[q*4+0] = (signed char)__float2int_rn(f.x);
            v[q*4+1] = (signed char)__float2int_rn(f.y);
            v[q*4+2] = (signed char)__float2int_rn(f.z);
            v[q*4+3] = (signed char)__float2int_rn(f.w);
        }
        *(int4*)(xf + (size_t)u * 16) = *(const int4*)v;
    } else if (b < 19520) {   // wp -> fragment layout (K=4096, KT=64)
        const int u   = (b - 19456) * 256 + tid;       // 16384 units
        const int g   = u >> 12;
        const int kt  = (u >> 6) & 63;
        const int l   = u & 63;
        const int row = g * 16 + (l & 15);
        const int k0  = kt * 64 + (l >> 4) * 16;
        const float4* src = (const float4*)(wp + (size_t)row * NH2 + k0);
        signed char v[16];
        #pragma unroll
        for (int q = 0; q < 4; ++q) {
            const float4 f = src[q];
            v[q*4+0] = (signed char)__float2int_rn(f.x);
            v[q*4+1] = (signed char)__float2int_rn(f.y);
            v[q*4+2] = (signed char)__float2int_rn(f.z);
            v[q*4+3] = (signed char)__float2int_rn(f.w);
        }
        *(int4*)(wpf + (size_t)u * 16) = *(const int4*)v;
    } else {   // sum_wp: S[a] = sum_k round(wp[a][k])
        const int a = b - 19520;
        int p = 0;
        for (int k = tid; k < NH2; k += 256) p += __float2int_rn(wp[(size_t)a * NH2 + k]);
        red[tid] = p; __syncthreads();
        for (int s = 128; s > 0; s >>= 1) { if (tid < s) red[tid] += red[tid + s]; __syncthreads(); }
        if (tid == 0) S[a] = red[0];
    }
}

// ---------------- i8 GEMM, C = A(MxK,FRAGMENT layout) * B(NxK row-major)^T ----------------
// 256x128 tile, BK=64, 8 waves (4Mx2N, wave 64x64), 2 blocks/CU.
// A-fragments direct from L2 (WAR-pinned read-ahead); B via 3-buffer LDS (counted vmcnt(1)).
// EPI=1: h1q = clip(round(relu(round(M*acc+b))/s),-128,127) -> out0 in FRAGMENT layout
// EPI=2: rr = relu(round(M*(acc+b))); FUSED HEAD: split rr into (lo-128),(hi-128) i8 planes
//        in LDS, multiply by wp-fragments via MFMA, atomicAdd u64 partials into part[8192][64].
template <int EPI>
__global__ __launch_bounds__(512, 4)
void gemm_af(const signed char* __restrict__ Af,
             const signed char* __restrict__ Bg,
             int M, int N, int K,
             const float* __restrict__ bias,
             const float* __restrict__ Mscale,
             const float* __restrict__ qscale,
             signed char* __restrict__ out0,
             const signed char* __restrict__ wpf,
             unsigned long long* __restrict__ part)
{
    // [0,24KB): 3 x 8KB B buffers; epilogue reuses as img planes (2 x 36864 = 73728)
    __shared__ __align__(16) signed char lds[73728];

    const int tid  = threadIdx.x;
    const int lane = tid & 63;
    const int wid  = tid >> 6;
    const int wm   = wid >> 1, wn = wid & 1;   // 4M x 2N waves, 64x64 each

    // XCD-aware bijective swizzle (grid divisible by 8), N-fastest
    const int nwg  = gridDim.x;
    const int bid  = blockIdx.x;
    const int swzb = (bid & 7) * (nwg >> 3) + (bid >> 3);
    const int nbx  = N >> 7;
    const int bx   = swzb % nbx;
    const int by   = swzb / nbx;
    const int bm0  = by << 8, bn0 = bx << 7;

    // B staging: 512 thr x 16B = 8KB tile (128 rows x 64B); XOR chunk swizzle
    const int srow = tid >> 2;
    const int sc   = (((tid & 3) ^ ((tid >> 3) & 3)) << 4);
    const signed char* bS = Bg + (size_t)(bn0 + srow) * K + sc;

    // B frag ds_read: lane -> row (lane&15), logical k-chunk lane>>4
    const int r    = lane & 15;
    const int pc   = (((lane >> 4) ^ ((r >> 1) & 3)) << 4);
    const int boff = wn * 4096 + r * 64 + pc;   // + n*1024

    // A fragment base: g = (bm0>>4) + wm*4 + m ; addr = ((g*NKT + kt)<<10) + lane*16
    const int NKT = K >> 6;
    const signed char* afB = Af + (((size_t)((bm0 >> 4) + wm * 4) * NKT) << 10) + lane * 16;

    const int nt = K >> 6;

    // prologue: af(0) x4 loads, stage B(0), B(1); vmcnt(1) ensures af+B0 done, B1 in flight
    v4i af[4], bf[4];
    #pragma unroll
    for (int m = 0; m < 4; ++m)
        af[m] = *(const v4i*)(afB + (((size_t)(m * NKT)) << 10));
    gload16(bS,      lds + tid * 16);
    gload16(bS + 64, lds + 8192 + tid * 16);
    asm volatile("s_waitcnt vmcnt(1)" ::: "memory");
    __builtin_amdgcn_s_barrier();

    v4i acc[4][4] = {};

    for (int t = 0; t < nt; ++t) {
        const signed char* L = lds + (t % 3) * 8192;
        #pragma unroll
        for (int n = 0; n < 4; ++n) bf[n] = *(const v4i*)(L + boff + n * 1024);

        const size_t tl = (size_t)((t + 1 < nt) ? (t + 1) : t);   // clamped read-ahead

        __builtin_amdgcn_s_setprio(1);
        #pragma unroll
        for (int m = 0; m < 4; ++m) {
            #pragma unroll
            for (int n = 0; n < 4; ++n)
                acc[m][n] = mfma_i8(af[m], bf[n], acc[m][n]);
            af[m] = *(const v4i*)(afB + (((size_t)(m * NKT) + tl) << 10));  // af(t+1), WAR-pinned
        }
        __builtin_amdgcn_s_setprio(0);

        if (t + 2 < nt) {
            gload16(bS + ((t + 2) << 6), lds + ((t + 2) % 3) * 8192 + tid * 16);
            asm volatile("s_waitcnt vmcnt(1)" ::: "memory");
        } else if (t + 1 < nt) {
            asm volatile("s_waitcnt vmcnt(0)" ::: "memory");
        }
        __builtin_amdgcn_s_barrier();
    }

    // ---- epilogue: LDS img [256][144] (16B-aligned rows) ----
    __syncthreads();
    signed char* img0 = lds;
    signed char* img1 = lds + 36864;
    const int rowb = wm * 64 + ((lane >> 4) << 2);
    const int colb = wn * 64 + (lane & 15);

    if constexpr (EPI == 1) {
        const float Mv = Mscale[0];
        const float sv = qscale[0];
        #pragma unroll
        for (int n = 0; n < 4; ++n) {
            const int col  = colb + n * 16;
            const int bint = __float2int_rn(bias[bn0 + col]);
            #pragma unroll
            for (int m = 0; m < 4; ++m) {
                #pragma unroll
                for (int j = 0; j < 4; ++j) {
                    const int row  = rowb + m * 16 + j;
                    const int accv = acc[m][n][j] + bint;      // |acc1| <= 8.4M: f32-exact
                    float h = rintf(Mv * (float)accv);
                    h = fmaxf(h, 0.0f);
                    float q = rintf(h / sv);
                    q = fminf(fmaxf(q, -128.0f), 127.0f);
                    img0[row * 144 + col] = (signed char)(int)q;
                }
            }
        }
        __syncthreads();
        // flush to FRAGMENT layout for GEMM2's A-side
        const int oNKT = N >> 6;
        #pragma unroll
        for (int i = 0; i < 4; ++i) {
            const int u    = i * 512 + tid;        // 2048 units x 16B
            const int g_l  = u >> 7;
            const int kt_l = (u >> 6) & 1;
            const int l    = u & 63;
            const int lrow = g_l * 16 + (l & 15);
            const int lcol = kt_l * 64 + (l >> 4) * 16;
            const size_t g  = (size_t)((bm0 >> 4) + g_l);
            const size_t kt = (size_t)((bn0 >> 6) + kt_l);
            *(int4*)(out0 + ((g * oNKT + kt) << 10) + l * 16) =
                *(const int4*)(img0 + lrow * 144 + lcol);
        }
    } else {
        const float Mv = Mscale[0];
        #pragma unroll
        for (int n = 0; n < 4; ++n) {
            const int col  = colb + n * 16;
            const int bint = __float2int_rn(bias[bn0 + col]);
            #pragma unroll
            for (int m = 0; m < 4; ++m) {
                #pragma unroll
                for (int j = 0; j < 4; ++j) {
                    const int row  = rowb + m * 16 + j;
                    const int accv = acc[m][n][j] + bint;      // |acc2| <= 66.6M: f64 exact
                    double rr = rint((double)Mv * (double)accv);
                    rr = rr > 0.0 ? rr : 0.0;                  // relu; <= 65024
                    const int v = (int)rr;
                    img0[row * 144 + col] = (signed char)((v & 255) - 128);
                    img1[row * 144 + col] = (signed char)((v >> 8) - 128);
                }
            }
        }
        __syncthreads();

        // ---- fused head: part[row][a] += sum_k (v[row][k]-32896)*wp[a][k] over this 128-col strip ----
        // B frags: wp fragment units (g=n a-group, kt = bn0>>6 + kk), NKT_wp = 64
        v4i bh[4][2];
        #pragma unroll
        for (int n = 0; n < 4; ++n)
            #pragma unroll
            for (int kk = 0; kk < 2; ++kk)
                bh[n][kk] = *(const v4i*)(wpf + (((size_t)(n * 64 + (bn0 >> 6) + kk)) << 10) + lane * 16);

        // A frags from img planes: wave handles rows [wid*32, wid*32+32)
        v4i accL[2][4] = {}, accH[2][4] = {};
        #pragma unroll
        for (int mm = 0; mm < 2; ++mm) {
            const int arow = (wid * 2 + mm) * 16 + (lane & 15);
            #pragma unroll
            for (int kk = 0; kk < 2; ++kk) {
                const int ka = kk * 64 + (lane >> 4) * 16;
                const v4i aL = *(const v4i*)(img0 + arow * 144 + ka);
                const v4i aH = *(const v4i*)(img1 + arow * 144 + ka);
                #pragma unroll
                for (int n = 0; n < 4; ++n) {
                    accL[mm][n] = mfma_i8(aL, bh[n][kk], accL[mm][n]);
                    accH[mm][n] = mfma_i8(aH, bh[n][kk], accH[mm][n]);
                }
            }
        }
        // atomic accumulate (u64, order-independent exact)
        #pragma unroll
        for (int mm = 0; mm < 2; ++mm) {
            #pragma unroll
            for (int n = 0; n < 4; ++n) {
                const int a = n * 16 + (lane & 15);
                #pragma unroll
                for (int j = 0; j < 4; ++j) {
                    const int row = bm0 + (wid * 2 + mm) * 16 + ((lane >> 4) << 2) + j;
                    const long long val = (long long)accL[mm][n][j] + 256LL * (long long)accH[mm][n][j];
                    atomicAdd(part + (size_t)row * NA + a, (unsigned long long)val);
                }
            }
        }
    }
}

// ---------------- combine: out = round(Mp*(part + 32896*S[a] + b[a])) ----------------
__global__ __launch_bounds__(256)
void comb_head(const unsigned long long* __restrict__ part, const int* __restrict__ S,
               const float* __restrict__ bp, const float* __restrict__ Mp,
               float* __restrict__ out)
{
    const int t = blockIdx.x * 256 + threadIdx.x;   // 524288
    const int a = t & 63;
    long long sum = (long long)part[t];
    sum += 32896LL * (long long)S[a] + (long long)__float2int_rn(bp[a]);
    out[t] = (float)rint((double)Mp[0] * (double)sum);
}

// ---------------- launcher ----------------
extern "C" void kernel_launch(void* const* d_in, const int* in_sizes, int n_in,
                              void* d_out, int out_size, void* d_ws, size_t ws_size,
                              hipStream_t stream) {
    const float* x  = (const float*)d_in[0];
    const float* w1 = (const float*)d_in[1];
    const float* b1 = (const float*)d_in[2];
    const float* w2 = (const float*)d_in[3];
    const float* b2 = (const float*)d_in[4];
    const float* wp = (const float*)d_in[7];
    const float* bp = (const float*)d_in[8];
    const float* M1 = (const float*)d_in[9];
    const float* M2 = (const float*)d_in[10];
    const float* Mp = (const float*)d_in[12];
    const float* s2 = (const float*)d_in[13];

    const size_t MB = (size_t)1 << 20;
    char* ws = (char*)d_ws;
    signed char* xf    = (signed char*)(ws);              // 4 MiB   x fragments
    signed char* w1_i8 = (signed char*)(ws + 4  * MB);    // 2 MiB
    signed char* w2_i8 = (signed char*)(ws + 6  * MB);    // 16 MiB
    signed char* wpf   = (signed char*)(ws + 22 * MB);    // 256 KiB wp fragments
    int*         Ssum  = (int*)        (ws + 22 * MB + 512 * 1024); // 256 B
    signed char* h1f   = (signed char*)(ws + 23 * MB);    // 32 MiB  h1q fragments
    unsigned long long* part = (unsigned long long*)(ws + 55 * MB); // 4 MiB u64 partials

    // all converts + sum_wp in one launch
    prep<<<dim3(19584), dim3(256), 0, stream>>>(x, w1, w2, wp, xf, w1_i8, w2_i8, wpf, Ssum);

    // GEMM1: (8192x512 frag) x (4096x512)^T -> h1f (fragment layout)
    gemm_af<1><<<dim3((NB / 256) * (NH1 / 128)), dim3(512), 0, stream>>>(
        xf, w1_i8, NB, NH1, DIN, b1, M1, s2, h1f, nullptr, nullptr);

    // zero head partials (stream-ordered, graph-capture safe)
    hipMemsetAsync(part, 0, (size_t)NB * NA * 8, stream);

    // GEMM2 + fused head: (8192x4096 frag) x (4096x4096)^T -> atomic partials
    gemm_af<2><<<dim3((NB / 256) * (NH2 / 128)), dim3(512), 0, stream>>>(
        h1f, w2_i8, NB, NH2, NH1, b2, M2, nullptr, nullptr, wpf, part);

    // combine
    comb_head<<<dim3(NB * NA / 256), dim3(256), 0, stream>>>(part, Ssum, bp, Mp, (float*)d_out);
}

// Round 11
// 200.780 us; speedup vs baseline: 1.2838x; 1.2838x over previous
//
#include <hip/hip_runtime.h>
#include <stdint.h>

#define NB   8192
#define DIN  512
#define NH1  4096
#define NH2  4096
#define NA   64

typedef int v4i __attribute__((ext_vector_type(4)));

__device__ __forceinline__ v4i mfma_i8(v4i a, v4i b, v4i c) {
    return __builtin_amdgcn_mfma_i32_16x16x64_i8(a, b, c, 0, 0, 0);
}

// ---- async global->LDS, 16B per lane (dest = wave-uniform base + lane*16) ----
__device__ __forceinline__ void gload16(const void* g, const void* l) {
    __builtin_amdgcn_global_load_lds(
        (const __attribute__((address_space(1))) void*)(uintptr_t)g,
        (__attribute__((address_space(3))) void*)(uint32_t)(uintptr_t)l,
        16, 0, 0);
}

// ---------------- merged prep: all converts + sum_wp in ONE launch ----------------
// blocks [0,16384): w2 | [16384,18432): w1 | [18432,19456): x->frag
// [19456,19712): wp row-major | [19712,19776): sum_wp
__global__ __launch_bounds__(256)
void prep(const float* __restrict__ x,  const float* __restrict__ w1,
          const float* __restrict__ w2, const float* __restrict__ wp,
          signed char* __restrict__ xf, signed char* __restrict__ w1_i8,
          signed char* __restrict__ w2_i8, signed char* __restrict__ wp_i8,
          int* __restrict__ S)
{
    __shared__ int red[256];
    const int b   = blockIdx.x;
    const int tid = threadIdx.x;

    if (b < 18432) {   // plain i8 converts (float4 -> char4)
        const float* in  = (b < 16384) ? w2 : w1;
        signed char* out = (b < 16384) ? w2_i8 : w1_i8;
        const int i = ((b < 16384) ? b : (b - 16384)) * 256 + tid;
        const float4 v = ((const float4*)in)[i];
        char4 c;
        c.x = (signed char)__float2int_rn(v.x);
        c.y = (signed char)__float2int_rn(v.y);
        c.z = (signed char)__float2int_rn(v.z);
        c.w = (signed char)__float2int_rn(v.w);
        ((char4*)out)[i] = c;
    } else if (b < 19456) {   // x -> fragment layout (K=512, KT=8)
        const int u   = (b - 18432) * 256 + tid;       // 262144 units
        const int g   = u >> 9;
        const int kt  = (u >> 6) & 7;
        const int l   = u & 63;
        const int row = g * 16 + (l & 15);
        const int k0  = kt * 64 + (l >> 4) * 16;
        const float4* src = (const float4*)(x + (size_t)row * DIN + k0);
        signed char v[16];
        #pragma unroll
        for (int q = 0; q < 4; ++q) {
            const float4 f = src[q];
            v[q*4+0] = (signed char)__float2int_rn(f.x);
            v[q*4+1] = (signed char)__float2int_rn(f.y);
            v[q*4+2] = (signed char)__float2int_rn(f.z);
            v[q*4+3] = (signed char)__float2int_rn(f.w);
        }
        *(int4*)(xf + (size_t)u * 16) = *(const int4*)v;
    } else if (b < 19712) {   // wp row-major i8 (64 x 4096)
        const int i = (b - 19456) * 256 + tid;         // 65536 char4 units
        const float4 v = ((const float4*)wp)[i];
        char4 c;
        c.x = (signed char)__float2int_rn(v.x);
        c.y = (signed char)__float2int_rn(v.y);
        c.z = (signed char)__float2int_rn(v.z);
        c.w = (signed char)__float2int_rn(v.w);
        ((char4*)wp_i8)[i] = c;
    } else {   // sum_wp: S[a] = sum_k round(wp[a][k])
        const int a = b - 19712;
        int p = 0;
        for (int k = tid; k < NH2; k += 256) p += __float2int_rn(wp[(size_t)a * NH2 + k]);
        red[tid] = p; __syncthreads();
        for (int s = 128; s > 0; s >>= 1) { if (tid < s) red[tid] += red[tid + s]; __syncthreads(); }
        if (tid == 0) S[a] = red[0];
    }
}

// ---------------- i8 GEMM, C = A(MxK,FRAGMENT layout) * B(NxK row-major)^T ----------------
// ROUND-8 PROVEN LOOP (verbatim): 256x128 tile, BK=64, 8 waves (4Mx2N, wave 64x64),
// 2 blocks/CU. A-fragments direct from L2 (WAR-pinned read-ahead); B via 3-buffer
// LDS (gload_lds + XOR swizzle); conservative vmcnt(1) after gload (sound with
// mixed load types — vmcnt>1 across types proved unsound in round 10).
// EPI=1: h1q -> out0 in FRAGMENT layout
// EPI=2: rr = relu(round(M*(acc+b))); out0=(rr&255)-128, out1=(rr>>8)-128 row-major planes
template <int EPI>
__global__ __launch_bounds__(512, 4)
void gemm_af(const signed char* __restrict__ Af,
             const signed char* __restrict__ Bg,
             int M, int N, int K,
             const float* __restrict__ bias,
             const float* __restrict__ Mscale,
             const float* __restrict__ qscale,
             signed char* __restrict__ out0,
             signed char* __restrict__ out1)
{
    // [0,24KB): 3 x 8KB B buffers; epilogue reuses as img planes (2 x 34816 = 69632)
    __shared__ __align__(16) signed char lds[69632];

    const int tid  = threadIdx.x;
    const int lane = tid & 63;
    const int wid  = tid >> 6;
    const int wm   = wid >> 1, wn = wid & 1;   // 4M x 2N waves, 64x64 each

    // XCD-aware bijective swizzle (grid divisible by 8), N-fastest
    const int nwg  = gridDim.x;
    const int bid  = blockIdx.x;
    const int swzb = (bid & 7) * (nwg >> 3) + (bid >> 3);
    const int nbx  = N >> 7;
    const int bx   = swzb % nbx;
    const int by   = swzb / nbx;
    const int bm0  = by << 8, bn0 = bx << 7;

    // B staging: 512 thr x 16B = 8KB tile (128 rows x 64B); XOR chunk swizzle
    const int srow = tid >> 2;
    const int sc   = (((tid & 3) ^ ((tid >> 3) & 3)) << 4);
    const signed char* bS = Bg + (size_t)(bn0 + srow) * K + sc;

    // B frag ds_read: lane -> row (lane&15), logical k-chunk lane>>4
    const int r    = lane & 15;
    const int pc   = (((lane >> 4) ^ ((r >> 1) & 3)) << 4);
    const int boff = wn * 4096 + r * 64 + pc;   // + n*1024

    // A fragment base: g = (bm0>>4) + wm*4 + m ; addr = ((g*NKT + kt)<<10) + lane*16
    const int NKT = K >> 6;
    const signed char* afB = Af + (((size_t)((bm0 >> 4) + wm * 4) * NKT) << 10) + lane * 16;

    const int nt = K >> 6;

    // prologue: af(0) x4 loads, stage B(0), B(1); vmcnt(1) ensures af+B0 done, B1 in flight
    v4i af[4], bf[4];
    #pragma unroll
    for (int m = 0; m < 4; ++m)
        af[m] = *(const v4i*)(afB + (((size_t)(m * NKT)) << 10));
    gload16(bS,      lds + tid * 16);
    gload16(bS + 64, lds + 8192 + tid * 16);
    asm volatile("s_waitcnt vmcnt(1)" ::: "memory");
    __builtin_amdgcn_s_barrier();

    v4i acc[4][4] = {};

    for (int t = 0; t < nt; ++t) {
        const signed char* L = lds + (t % 3) * 8192;
        #pragma unroll
        for (int n = 0; n < 4; ++n) bf[n] = *(const v4i*)(L + boff + n * 1024);

        const size_t tl = (size_t)((t + 1 < nt) ? (t + 1) : t);   // clamped read-ahead

        __builtin_amdgcn_s_setprio(1);
        #pragma unroll
        for (int m = 0; m < 4; ++m) {
            #pragma unroll
            for (int n = 0; n < 4; ++n)
                acc[m][n] = mfma_i8(af[m], bf[n], acc[m][n]);
            af[m] = *(const v4i*)(afB + (((size_t)(m * NKT) + tl) << 10));  // af(t+1), WAR-pinned
        }
        __builtin_amdgcn_s_setprio(0);

        if (t + 2 < nt) {
            gload16(bS + ((t + 2) << 6), lds + ((t + 2) % 3) * 8192 + tid * 16);
            asm volatile("s_waitcnt vmcnt(1)" ::: "memory");
        } else if (t + 1 < nt) {
            asm volatile("s_waitcnt vmcnt(0)" ::: "memory");
        }
        __builtin_amdgcn_s_barrier();
    }

    // ---- epilogue: LDS img [256][136] per plane (round-8 proven, 0 conflicts) ----
    __syncthreads();
    signed char* img0 = lds;
    signed char* img1 = lds + 34816;
    const int rowb = wm * 64 + ((lane >> 4) << 2);
    const int colb = wn * 64 + (lane & 15);

    if constexpr (EPI == 1) {
        const float Mv = Mscale[0];
        const float sv = qscale[0];
        #pragma unroll
        for (int n = 0; n < 4; ++n) {
            const int col  = colb + n * 16;
            const int bint = __float2int_rn(bias[bn0 + col]);
            #pragma unroll
            for (int m = 0; m < 4; ++m) {
                #pragma unroll
                for (int j = 0; j < 4; ++j) {
                    const int row  = rowb + m * 16 + j;
                    const int accv = acc[m][n][j] + bint;      // |acc1| <= 8.4M: f32-exact
                    float h = rintf(Mv * (float)accv);
                    h = fmaxf(h, 0.0f);
                    float q = rintf(h / sv);
                    q = fminf(fmaxf(q, -128.0f), 127.0f);
                    img0[row * 136 + col] = (signed char)(int)q;
                }
            }
        }
        __syncthreads();
        // flush to FRAGMENT layout for GEMM2's A-side
        const int oNKT = N >> 6;
        #pragma unroll
        for (int i = 0; i < 4; ++i) {
            const int u    = i * 512 + tid;        // 2048 units x 16B
            const int g_l  = u >> 7;
            const int kt_l = (u >> 6) & 1;
            const int l    = u & 63;
            const int lrow = g_l * 16 + (l & 15);
            const int lcol = kt_l * 64 + (l >> 4) * 16;
            const size_t g  = (size_t)((bm0 >> 4) + g_l);
            const size_t kt = (size_t)((bn0 >> 6) + kt_l);
            *(int4*)(out0 + ((g * oNKT + kt) << 10) + l * 16) =
                *(const int4*)(img0 + lrow * 136 + lcol);
        }
    } else {
        const float Mv = Mscale[0];
        #pragma unroll
        for (int n = 0; n < 4; ++n) {
            const int col  = colb + n * 16;
            const int bint = __float2int_rn(bias[bn0 + col]);
            #pragma unroll
            for (int m = 0; m < 4; ++m) {
                #pragma unroll
                for (int j = 0; j < 4; ++j) {
                    const int row  = rowb + m * 16 + j;
                    const int accv = acc[m][n][j] + bint;      // |acc2| <= 66.6M: f64 exact
                    double rr = rint((double)Mv * (double)accv);
                    rr = rr > 0.0 ? rr : 0.0;                  // relu; <= 65024
                    const int v = (int)rr;
                    img0[row * 136 + col] = (signed char)((v & 255) - 128);
                    img1[row * 136 + col] = (signed char)((v >> 8) - 128);
                }
            }
        }
        __syncthreads();
        #pragma unroll
        for (int p = 0; p < 8; ++p) {
            const int idx = p * 512 + tid;
            const int row = idx >> 4;
            const int cb  = (idx & 15) * 8;
            const size_t gaddr = (size_t)(bm0 + row) * N + bn0 + cb;
            *(int2*)(out0 + gaddr) = *(const int2*)(img0 + row * 136 + cb);
            *(int2*)(out1 + gaddr) = *(const int2*)(img1 + row * 136 + cb);
        }
    }
}

// ---------------- head MFMA: partial[kblk][r][a] = 256*Phi + Plo over K-chunk 512 ----------------
__global__ __launch_bounds__(512, 1)
void head_mfma(const signed char* __restrict__ lo,
               const signed char* __restrict__ hi,
               const signed char* __restrict__ wpq,
               int* __restrict__ part)
{
    __shared__ __align__(16) signed char Bl[32768];       // 64 x 512 i8 (swizzled)
    __shared__ __align__(16) signed char Al[3][32768];    // [lo 256x64 | hi 256x64]

    const int tid  = threadIdx.x;
    const int lane = tid & 63;
    const int wid  = tid >> 6;
    const int rblk = blockIdx.x >> 3;
    const int kblk = blockIdx.x & 7;
    const int bm0  = rblk << 8;
    const int kb   = kblk << 9;

    #pragma unroll
    for (int s = 0; s < 4; ++s) {
        const int brow = s * 16 + (tid >> 5);
        const int pch  = tid & 31;
        const int lc   = pch ^ (brow & 7);
        gload16(wpq + (size_t)brow * NH2 + kb + lc * 16, Bl + brow * 512 + pch * 16);
    }

    const int srow  = tid >> 2;
    const int sclog = (tid & 3) ^ ((tid >> 3) & 3);
    const size_t ab = (size_t)(bm0 + srow) * NH2 + kb + sclog * 16;
    const size_t rK = (size_t)128 * NH2;

    #define HSTAGE(bp, ko) do { \
        gload16(lo + ab + (ko),      &Al[bp][0]     + tid * 16); \
        gload16(lo + ab + rK + (ko), &Al[bp][8192]  + tid * 16); \
        gload16(hi + ab + (ko),      &Al[bp][16384] + tid * 16); \
        gload16(hi + ab + rK + (ko), &Al[bp][24576] + tid * 16); } while (0)

    HSTAGE(0, 0);
    HSTAGE(1, 64);

    const int r    = lane & 15;
    const int cg   = lane >> 4;
    const int pcA  = (cg ^ ((r >> 1) & 3)) * 16;
    const int aoff = wid * 2048 + r * 64 + pcA;

    v4i accL[2][4] = {}, accH[2][4] = {};
    int cur = 0, nxt = 2;

    for (int t = 0; t < 8; ++t) {
        if (t < 7) asm volatile("s_waitcnt vmcnt(4)" ::: "memory");
        else       asm volatile("s_waitcnt vmcnt(0)" ::: "memory");
        __builtin_amdgcn_s_barrier();

        const signed char* A = &Al[cur][0];
        v4i bf[4], al[2], ah[2];
        #pragma unroll
        for (int n = 0; n < 4; ++n)
            bf[n] = *(const v4i*)(Bl + (n * 16 + r) * 512 + (((t * 4 + cg) ^ (r & 7)) * 16));
        #pragma unroll
        for (int m = 0; m < 2; ++m) al[m] = *(const v4i*)(A + aoff + m * 1024);
        #pragma unroll
        for (int m = 0; m < 2; ++m) ah[m] = *(const v4i*)(A + 16384 + aoff + m * 1024);

        if (t + 2 < 8) HSTAGE(nxt, (t + 2) << 6);

        __builtin_amdgcn_s_setprio(1);
        #pragma unroll
        for (int m = 0; m < 2; ++m)
            #pragma unroll
            for (int n = 0; n < 4; ++n) {
                accL[m][n] = mfma_i8(al[m], bf[n], accL[m][n]);
                accH[m][n] = mfma_i8(ah[m], bf[n], accH[m][n]);
            }
        __builtin_amdgcn_s_setprio(0);
        __builtin_amdgcn_s_barrier();

        cur = (cur == 2) ? 0 : cur + 1;
        nxt = (nxt == 2) ? 0 : nxt + 1;
    }
    #undef HSTAGE

    int* pb = part + (size_t)kblk * (NB * NA);
    const int rowb = bm0 + wid * 32 + ((lane >> 4) << 2);
    #pragma unroll
    for (int m = 0; m < 2; ++m)
        #pragma unroll
        for (int n = 0; n < 4; ++n) {
            const int a = n * 16 + (lane & 15);
            #pragma unroll
            for (int j = 0; j < 4; ++j) {
                const int row = rowb + m * 16 + j;
                pb[(size_t)row * NA + a] = accL[m][n][j] + (accH[m][n][j] << 8);
            }
        }
}

// ---------------- combine: out = round(Mp*(sum parts + 32896*S[a] + b[a])) ----------------
__global__ __launch_bounds__(256)
void comb_head(const int* __restrict__ part, const int* __restrict__ S,
               const float* __restrict__ bp, const float* __restrict__ Mp,
               float* __restrict__ out)
{
    const int t = blockIdx.x * 256 + threadIdx.x;   // 524288
    const int a = t & 63;
    long long sum = 0;
    #pragma unroll
    for (int c = 0; c < 8; ++c) sum += part[(size_t)c * (NB * NA) + t];
    sum += 32896LL * (long long)S[a] + (long long)__float2int_rn(bp[a]);
    out[t] = (float)rint((double)Mp[0] * (double)sum);
}

// ---------------- launcher ----------------
extern "C" void kernel_launch(void* const* d_in, const int* in_sizes, int n_in,
                              void* d_out, int out_size, void* d_ws, size_t ws_size,
                              hipStream_t stream) {
    const float* x  = (const float*)d_in[0];
    const float* w1 = (const float*)d_in[1];
    const float* b1 = (const float*)d_in[2];
    const float* w2 = (const float*)d_in[3];
    const float* b2 = (const float*)d_in[4];
    const float* wp = (const float*)d_in[7];
    const float* bp = (const float*)d_in[8];
    const float* M1 = (const float*)d_in[9];
    const float* M2 = (const float*)d_in[10];
    const float* Mp = (const float*)d_in[12];
    const float* s2 = (const float*)d_in[13];

    const size_t MB = (size_t)1 << 20;
    char* ws = (char*)d_ws;
    signed char* xf    = (signed char*)(ws);              // 4 MiB   x fragments
    signed char* w1_i8 = (signed char*)(ws + 4  * MB);    // 2 MiB
    signed char* w2_i8 = (signed char*)(ws + 6  * MB);    // 16 MiB
    signed char* wp_i8 = (signed char*)(ws + 22 * MB);    // 256 KiB row-major
    int*         Ssum  = (int*)        (ws + 22 * MB + 512 * 1024); // 256 B
    signed char* h1f   = (signed char*)(ws + 23 * MB);    // 32 MiB  h1q fragments
    signed char* h2lo  = (signed char*)(ws + 55 * MB);    // 32 MiB
    signed char* h2hi  = (signed char*)(ws + 87 * MB);    // 32 MiB
    int*         part  = (int*)        (ws);              // 16 MiB, overlays xf/w1/w2 (post-GEMM2)

    // all converts + sum_wp in one launch
    prep<<<dim3(19776), dim3(256), 0, stream>>>(x, w1, w2, wp, xf, w1_i8, w2_i8, wp_i8, Ssum);

    // GEMM1: (8192x512 frag) x (4096x512)^T -> h1f (fragment layout)
    gemm_af<1><<<dim3((NB / 256) * (NH1 / 128)), dim3(512), 0, stream>>>(
        xf, w1_i8, NB, NH1, DIN, b1, M1, s2, h1f, nullptr);
    // GEMM2: (8192x4096 frag) x (4096x4096)^T -> h2lo/h2hi i8 planes (row-major)
    gemm_af<2><<<dim3((NB / 256) * (NH2 / 128)), dim3(512), 0, stream>>>(
        h1f, w2_i8, NB, NH2, NH1, b2, M2, nullptr, h2lo, h2hi);
    // head: 256 blocks (32 row-tiles x 8 K-chunks) -> part, then combine
    head_mfma<<<dim3(256), dim3(512), 0, stream>>>(h2lo, h2hi, wp_i8, part);
    comb_head<<<dim3(NB * NA / 256), dim3(256), 0, stream>>>(part, Ssum, bp, Mp, (float*)d_out);
}